// Round 3
// baseline (3101.893 us; speedup 1.0000x reference)
//
#include <hip/hip_runtime.h>
#include <math.h>

typedef unsigned short ushort;
typedef unsigned int uint;
typedef __attribute__((ext_vector_type(8))) short bf16x8;
typedef __attribute__((ext_vector_type(4))) float f32x4;

#define B_  32
#define S_  24
#define T_  24
#define E_  620
#define EP_ 640
#define H_  1000
#define HP_ 1024
#define V_  30000
#define M2_ 1000
#define KW_ 512
#define NB_ 126

__device__ __forceinline__ ushort f2bf(float f) {
  uint u = __float_as_uint(f);
  u += 0x7FFFu + ((u >> 16) & 1u);
  return (ushort)(u >> 16);
}

// ---------------------------------------------------------------------------
// weight conversion: fp32 [vrows][K] -> bf16 [arows][Kp], zero padded rows/cols
// ---------------------------------------------------------------------------
struct ConvJobs {
  const float* in[18];
  ushort* out[18];
  int K[18], Kp[18], vrows[18], arows[18];
};
__global__ __launch_bounds__(256) void conv_small(ConvJobs a) {
  int j = blockIdx.y, row = blockIdx.x;
  if (row >= a.arows[j]) return;
  ushort* op = a.out[j] + (size_t)row * a.Kp[j];
  if (row >= a.vrows[j]) {
    for (int k = threadIdx.x; k < a.Kp[j]; k += 256) op[k] = 0;
    return;
  }
  const float* ip = a.in[j] + (size_t)row * a.K[j];
  for (int k = threadIdx.x; k < a.Kp[j]; k += 256)
    op[k] = (k < a.K[j]) ? f2bf(ip[k]) : (ushort)0;
}

// ---------------------------------------------------------------------------
// embedding gather -> bf16, K padded 620->640; row r = step*32 + b
// ---------------------------------------------------------------------------
__global__ __launch_bounds__(256) void gather16(
    const int* __restrict__ src, const int* __restrict__ tgt,
    const float* __restrict__ semb, const float* __restrict__ temb,
    ushort* __restrict__ XE, ushort* __restrict__ YE) {
  int row = blockIdx.x;
  int isT = row >= S_ * B_;
  int r = isT ? row - S_ * B_ : row;
  int st = r >> 5, b = r & 31;
  int tok = isT ? tgt[b * T_ + st] : src[b * S_ + st];
  const float* e = (isT ? temb : semb) + (size_t)tok * E_;
  ushort* o = (isT ? YE : XE) + (size_t)r * EP_;
  for (int k = threadIdx.x; k < EP_; k += 256)
    o[k] = (k < E_) ? f2bf(e[k]) : (ushort)0;
}

// ---------------------------------------------------------------------------
// bf16 MFMA GEMM: C = A @ Bw^T. A [M][Kp] bf16 (stride Kp).
// B either bf16 [N][Kp] (Bw) or fp32 [N][ldbF] (BwF, converted in staging).
// mode 0: fp32 store; mode 1: maxout -> bf16 tmax; mode 2: scatter rows (t,b).
// swz: 1-D grid, XCD-grouped so M-tiles sharing an N-tile land on one XCD.
// ---------------------------------------------------------------------------
struct MG {
  const ushort* A[8];
  const ushort* Bw[8];
  const float* BwF;
  float* C[8];
  int M, N, Kp, ldc;
  int mode;
  const float* e1;
  const float* e2;
  ushort* tmax;
  int bF32, Kreal, ldbF, swz;
};

__global__ __launch_bounds__(256) void mgemm(MG g) {
  __shared__ ushort As[128 * 40];
  __shared__ ushort Bs[128 * 40];
  int bx, by;
  if (g.swz) {
    int bid = blockIdx.x;
    int xcd = bid & 7, j = bid >> 3;
    int tn = xcd + 8 * (j / 6);
    if (tn >= (g.N + 127) >> 7) return;
    bx = tn; by = j % 6;
  } else {
    bx = blockIdx.x; by = blockIdx.y;
  }
  const int z = blockIdx.z;
  const ushort* __restrict__ A = g.A[z];
  const int tid = threadIdx.x;
  const int wave = tid >> 6, lane = tid & 63;
  const int lm = lane & 15, kq = lane >> 4;
  const int wm = (wave >> 1) * 64, wn = (wave & 1) * 64;
  const int m0 = by * 128, n0 = bx * 128;
  const int Kp = g.Kp;

  f32x4 acc[4][4];
#pragma unroll
  for (int i = 0; i < 4; ++i)
#pragma unroll
    for (int j = 0; j < 4; ++j) acc[i][j] = (f32x4){0.f, 0.f, 0.f, 0.f};

  const int row_s = tid >> 2, seg = tid & 3;

  for (int k0 = 0; k0 < Kp; k0 += 32) {
#pragma unroll
    for (int p = 0; p < 2; ++p) {
      int row = row_s + p * 64;
      int gm = m0 + row;
      uint4 va = make_uint4(0, 0, 0, 0);
      if (gm < g.M) va = *(const uint4*)(A + (size_t)gm * Kp + k0 + seg * 8);
      *(uint4*)&As[row * 40 + seg * 8] = va;
      int gn = n0 + row;
      if (!g.bF32) {
        uint4 vb = make_uint4(0, 0, 0, 0);
        if (gn < g.N) vb = *(const uint4*)(g.Bw[z] + (size_t)gn * Kp + k0 + seg * 8);
        *(uint4*)&Bs[row * 40 + seg * 8] = vb;
      } else {
        int kb = k0 + seg * 8;
        float4 f0 = make_float4(0.f, 0.f, 0.f, 0.f), f1 = f0;
        if (gn < g.N) {
          const float* bp = g.BwF + (size_t)gn * g.ldbF;
          if (kb < g.Kreal) f0 = *(const float4*)(bp + kb);
          if (kb + 4 < g.Kreal) f1 = *(const float4*)(bp + kb + 4);
        }
        ushort* d = &Bs[row * 40 + seg * 8];
        d[0] = f2bf(f0.x); d[1] = f2bf(f0.y); d[2] = f2bf(f0.z); d[3] = f2bf(f0.w);
        d[4] = f2bf(f1.x); d[5] = f2bf(f1.y); d[6] = f2bf(f1.z); d[7] = f2bf(f1.w);
      }
    }
    __syncthreads();
    bf16x8 af[4], bfr[4];
#pragma unroll
    for (int i = 0; i < 4; ++i)
      af[i] = *(const bf16x8*)&As[(wm + i * 16 + lm) * 40 + kq * 8];
#pragma unroll
    for (int j = 0; j < 4; ++j)
      bfr[j] = *(const bf16x8*)&Bs[(wn + j * 16 + lm) * 40 + kq * 8];
#pragma unroll
    for (int i = 0; i < 4; ++i)
#pragma unroll
      for (int j = 0; j < 4; ++j)
        acc[i][j] = __builtin_amdgcn_mfma_f32_16x16x32_bf16(af[i], bfr[j], acc[i][j], 0, 0, 0);
    __syncthreads();
  }

#pragma unroll
  for (int i = 0; i < 4; ++i) {
    int grow = m0 + wm + i * 16 + kq * 4;
#pragma unroll
    for (int j = 0; j < 4; ++j) {
      int gcol = n0 + wn + j * 16 + lm;
#pragma unroll
      for (int r = 0; r < 4; ++r) {
        int row = grow + r;
        float v = acc[i][j][r];
        if (g.mode == 0) {
          if (row < g.M && gcol < g.N) g.C[z][(size_t)row * g.ldc + gcol] = v;
        } else if (g.mode == 1) {
          float vv = v;
          if (row < g.M && gcol < g.N)
            vv += g.e1[(size_t)row * M2_ + gcol] + g.e2[(size_t)(row & 31) * M2_ + gcol];
          float other = __shfl_xor(vv, 1);
          if ((lane & 1) == 0 && row < g.M && gcol < g.N)
            g.tmax[(size_t)row * KW_ + (gcol >> 1)] = f2bf(fmaxf(vv, other));
        } else {
          if (row < g.M && gcol < g.N) {
            int t = row >> 5, b = row & 31;
            g.C[z][((size_t)b * T_ + t) * (size_t)g.ldc + gcol] = v;
          }
        }
      }
    }
  }
}

// ---------------------------------------------------------------------------
// Persistent recurrence kernel: encoder scan + context proj + decoder scan.
// 126 blocks x 256 thr. Phase A: 126 tile jobs (r,z gates, 63 x 16-col tiles
// each). Phase B: 63 tile jobs (cand + state update). Custom grid barrier.
// ---------------------------------------------------------------------------
struct RecArgs {
  const ushort *encUr, *encUz, *encU, *decUr, *decUz, *decU;
  const ushort *cW0, *cW1, *cW2, *cW3, *cW4;   // dec_Cr, dec_Cz, dec_C, C_o, W_s
  const float *XPr, *XPz, *XPc, *YPr, *YPz, *YPc;
  const float *enc_b, *enc_bz, *enc_br, *dec_b, *dec_bz, *dec_br;
  float* hf; ushort* h16;     // encoder state (fp32 master + bf16 mirror)
  float* sdf; ushort* hd16;   // decoder state
  ushort* rh16; float* zbuf;
  float *cCr, *cCz, *cC, *cCo;
  ushort* Srm;                // [24][32][1024] bf16
  uint* bar;
};

__device__ __forceinline__ void gbar(uint* bar, uint* phase) {
  __threadfence();
  __syncthreads();
  if (threadIdx.x == 0) {
    __hip_atomic_fetch_add(bar, 1u, __ATOMIC_RELAXED, __HIP_MEMORY_SCOPE_AGENT);
    uint target = ++(*phase) * NB_;
    while (__hip_atomic_load(bar, __ATOMIC_RELAXED, __HIP_MEMORY_SCOPE_AGENT) < target)
      __builtin_amdgcn_s_sleep(1);
  }
  __syncthreads();
  __threadfence();
}

// [32 x 16] output tile partial for this wave over its K-quarter.
// A16: [32][1024] bf16; W16: [>=1008][1024] bf16, row = output col.
__device__ __forceinline__ void mm_tile(const ushort* __restrict__ A16,
                                        const ushort* __restrict__ W16,
                                        int col0, f32x4* acc) {
  const int lane = threadIdx.x & 63;
  const int lm = lane & 15, kq = lane >> 4;
  const int wv = threadIdx.x >> 6;
  const ushort* wrow = W16 + (size_t)(col0 + lm) * HP_ + kq * 8;
  const ushort* ar0 = A16 + lm * HP_ + kq * 8;
  const ushort* ar1 = ar0 + 16 * HP_;
  const int kb = wv * 256;
#pragma unroll
  for (int ks = 0; ks < 8; ++ks) {
    int k = kb + ks * 32;
    bf16x8 b  = *(const bf16x8*)(wrow + k);
    bf16x8 a0 = *(const bf16x8*)(ar0 + k);
    bf16x8 a1 = *(const bf16x8*)(ar1 + k);
    acc[0] = __builtin_amdgcn_mfma_f32_16x16x32_bf16(a0, b, acc[0], 0, 0, 0);
    acc[1] = __builtin_amdgcn_mfma_f32_16x16x32_bf16(a1, b, acc[1], 0, 0, 0);
  }
}

__device__ __forceinline__ void stash(float red[4][32][16], const f32x4* acc) {
  const int lane = threadIdx.x & 63;
  const int lm = lane & 15, kq = lane >> 4;
  const int wv = threadIdx.x >> 6;
#pragma unroll
  for (int mf = 0; mf < 2; ++mf)
#pragma unroll
    for (int r = 0; r < 4; ++r)
      red[wv][mf * 16 + kq * 4 + r][lm] = acc[mf][r];
}

__global__ __launch_bounds__(256, 1) void rnn_rec(RecArgs a) {
  __shared__ float red[4][32][16];
  const int bid = blockIdx.x;
  const int tid = threadIdx.x;
  uint phase = 0;

  // ---------------- encoder ----------------
  for (int s = 0; s < S_; ++s) {
    {  // phase A: r (mat 0) and z (mat 1) gates
      int mat = bid / 63, tile = bid % 63, col0 = tile * 16;
      f32x4 acc[2] = {(f32x4){0.f,0.f,0.f,0.f}, (f32x4){0.f,0.f,0.f,0.f}};
      mm_tile(a.h16, mat == 0 ? a.encUr : a.encUz, col0, acc);
      stash(red, acc);
      __syncthreads();
      const float* Xp = (mat == 0 ? a.XPr : a.XPz) + s * 32000;
      const float* bias = mat == 0 ? a.enc_br : a.enc_bz;
#pragma unroll
      for (int rep = 0; rep < 2; ++rep) {
        int idx = rep * 256 + tid;
        int b = idx >> 4, c = idx & 15;
        int col = col0 + c;
        if (col < H_) {
          float sum = red[0][b][c] + red[1][b][c] + red[2][b][c] + red[3][b][c];
          int o = b * H_ + col;
          float g = 1.f / (1.f + expf(-(sum + Xp[o] + bias[col])));
          if (mat == 0)
            a.rh16[b * HP_ + col] = f2bf(g * a.hf[b * HP_ + col]);
          else
            a.zbuf[o] = g;
        }
      }
    }
    gbar(a.bar, &phase);
    if (bid < 63) {  // phase B: cand + update
      int col0 = bid * 16;
      f32x4 acc[2] = {(f32x4){0.f,0.f,0.f,0.f}, (f32x4){0.f,0.f,0.f,0.f}};
      mm_tile(a.rh16, a.encU, col0, acc);
      stash(red, acc);
      __syncthreads();
#pragma unroll
      for (int rep = 0; rep < 2; ++rep) {
        int idx = rep * 256 + tid;
        int b = idx >> 4, c = idx & 15;
        int col = col0 + c;
        if (col < H_) {
          float sum = red[0][b][c] + red[1][b][c] + red[2][b][c] + red[3][b][c];
          int o = b * H_ + col;
          float cand = tanhf(sum + a.XPc[s * 32000 + o] + a.enc_b[col]);
          float z = a.zbuf[o];
          float old = a.hf[b * HP_ + col];
          float nv = (1.f - z) * old + z * cand;
          a.hf[b * HP_ + col] = nv;
          a.h16[b * HP_ + col] = f2bf(nv);
        }
      }
    }
    gbar(a.bar, &phase);
  }

  // ---------------- context projections + s0 ----------------
  for (int job = bid; job < 315; job += NB_) {
    int mat = job / 63, tile = job % 63, col0 = tile * 16;
    const ushort* W = mat == 0 ? a.cW0 : mat == 1 ? a.cW1 : mat == 2 ? a.cW2
                    : mat == 3 ? a.cW3 : a.cW4;
    f32x4 acc[2] = {(f32x4){0.f,0.f,0.f,0.f}, (f32x4){0.f,0.f,0.f,0.f}};
    mm_tile(a.h16, W, col0, acc);
    stash(red, acc);
    __syncthreads();
#pragma unroll
    for (int rep = 0; rep < 2; ++rep) {
      int idx = rep * 256 + tid;
      int b = idx >> 4, c = idx & 15;
      int col = col0 + c;
      if (col < H_) {
        float sum = red[0][b][c] + red[1][b][c] + red[2][b][c] + red[3][b][c];
        int o = b * H_ + col;
        if (mat == 0) a.cCr[o] = sum;
        else if (mat == 1) a.cCz[o] = sum;
        else if (mat == 2) a.cC[o] = sum;
        else if (mat == 3) a.cCo[o] = sum;
        else {
          float v = tanhf(sum);
          a.sdf[b * HP_ + col] = v;
          a.hd16[b * HP_ + col] = f2bf(v);
          a.Srm[b * HP_ + col] = f2bf(v);
        }
      }
    }
    __syncthreads();
  }
  gbar(a.bar, &phase);

  // ---------------- decoder ----------------
  for (int t = 0; t < T_ - 1; ++t) {
    {  // phase A
      int mat = bid / 63, tile = bid % 63, col0 = tile * 16;
      f32x4 acc[2] = {(f32x4){0.f,0.f,0.f,0.f}, (f32x4){0.f,0.f,0.f,0.f}};
      mm_tile(a.hd16, mat == 0 ? a.decUr : a.decUz, col0, acc);
      stash(red, acc);
      __syncthreads();
      const float* Xp = (mat == 0 ? a.YPr : a.YPz) + t * 32000;
      const float* cc = mat == 0 ? a.cCr : a.cCz;
      const float* bias = mat == 0 ? a.dec_br : a.dec_bz;
#pragma unroll
      for (int rep = 0; rep < 2; ++rep) {
        int idx = rep * 256 + tid;
        int b = idx >> 4, c = idx & 15;
        int col = col0 + c;
        if (col < H_) {
          float sum = red[0][b][c] + red[1][b][c] + red[2][b][c] + red[3][b][c];
          int o = b * H_ + col;
          float g = 1.f / (1.f + expf(-(sum + Xp[o] + cc[o] + bias[col])));
          if (mat == 0)
            a.rh16[b * HP_ + col] = f2bf(g * a.sdf[b * HP_ + col]);
          else
            a.zbuf[o] = g;
        }
      }
    }
    gbar(a.bar, &phase);
    if (bid < 63) {  // phase B
      int col0 = bid * 16;
      f32x4 acc[2] = {(f32x4){0.f,0.f,0.f,0.f}, (f32x4){0.f,0.f,0.f,0.f}};
      mm_tile(a.rh16, a.decU, col0, acc);
      stash(red, acc);
      __syncthreads();
#pragma unroll
      for (int rep = 0; rep < 2; ++rep) {
        int idx = rep * 256 + tid;
        int b = idx >> 4, c = idx & 15;
        int col = col0 + c;
        if (col < H_) {
          float sum = red[0][b][c] + red[1][b][c] + red[2][b][c] + red[3][b][c];
          int o = b * H_ + col;
          float cand = tanhf(sum + a.YPc[t * 32000 + o] + a.cC[o] + a.dec_b[col]);
          float z = a.zbuf[o];
          float old = a.sdf[b * HP_ + col];
          float nv = (1.f - z) * old + z * cand;
          a.sdf[b * HP_ + col] = nv;
          a.hd16[b * HP_ + col] = f2bf(nv);
          a.Srm[(size_t)(t + 1) * B_ * HP_ + b * HP_ + col] = f2bf(nv);
        }
      }
    }
    gbar(a.bar, &phase);
  }
}

// ---------------------------------------------------------------------------
// Host
// ---------------------------------------------------------------------------
extern "C" void kernel_launch(void* const* d_in, const int* in_sizes, int n_in,
                              void* d_out, int out_size, void* d_ws, size_t ws_size,
                              hipStream_t stream) {
  const int*   src     = (const int*)d_in[0];
  const int*   tgt     = (const int*)d_in[1];
  const float* src_emb = (const float*)d_in[3];
  const float* tgt_emb = (const float*)d_in[4];
  const float* enc_W   = (const float*)d_in[5];
  const float* enc_Wz  = (const float*)d_in[6];
  const float* enc_Wr  = (const float*)d_in[7];
  const float* enc_U   = (const float*)d_in[8];
  const float* enc_Uz  = (const float*)d_in[9];
  const float* enc_Ur  = (const float*)d_in[10];
  const float* enc_b   = (const float*)d_in[11];
  const float* enc_bz  = (const float*)d_in[12];
  const float* enc_br  = (const float*)d_in[13];
  const float* dec_W   = (const float*)d_in[14];
  const float* dec_Wz  = (const float*)d_in[15];
  const float* dec_Wr  = (const float*)d_in[16];
  const float* dec_U   = (const float*)d_in[17];
  const float* dec_Uz  = (const float*)d_in[18];
  const float* dec_Ur  = (const float*)d_in[19];
  const float* dec_C   = (const float*)d_in[20];
  const float* dec_Cz  = (const float*)d_in[21];
  const float* dec_Cr  = (const float*)d_in[22];
  const float* dec_b   = (const float*)d_in[23];
  const float* dec_bz  = (const float*)d_in[24];
  const float* dec_br  = (const float*)d_in[25];
  const float* W_s     = (const float*)d_in[26];
  const float* U_o     = (const float*)d_in[27];
  const float* V_o     = (const float*)d_in[28];
  const float* C_o     = (const float*)d_in[29];
  const float* W_o     = (const float*)d_in[30];
  float* out = (float*)d_out;
  char* wsb = (char*)d_ws;
  (void)in_sizes; (void)n_in; (void)out_size; (void)ws_size;

  uint*   bar   = (uint*)(wsb + 0);
  float*  hf    = (float*)(wsb + 256);
  ushort* h16   = (ushort*)(wsb + 131328);
  float*  sdf   = (float*)(wsb + 196864);
  ushort* hd16  = (ushort*)(wsb + 327936);
  ushort* rh16  = (ushort*)(wsb + 393472);
  ushort* Srm16 = (ushort*)(wsb + 459008);    // 24*32*1024 bf16
  ushort* Tmax  = (ushort*)(wsb + 2031872);   // 768*512 bf16
  // zero block = [0, 2818304)
  float*  zbuf  = (float*)(wsb + 2818304);
  float*  cCr   = (float*)(wsb + 2946304);
  float*  cCz   = (float*)(wsb + 3074304);
  float*  cC    = (float*)(wsb + 3202304);
  float*  cCo   = (float*)(wsb + 3330304);
  float*  YV    = (float*)(wsb + 3458304);    // 768*1000 f32
  float*  XPr   = (float*)(wsb + 6530304);
  float*  XPz   = (float*)(wsb + 9602304);
  float*  XPc   = (float*)(wsb + 12674304);
  float*  YPr   = (float*)(wsb + 15746304);
  float*  YPz   = (float*)(wsb + 18818304);
  float*  YPc   = (float*)(wsb + 21890304);
  ushort* XE16  = (ushort*)(wsb + 24962304);  // 768*640 bf16
  ushort* YE16  = (ushort*)(wsb + 25945344);
  ushort* H16   = (ushort*)(wsb + 26928384);  // 11 x 1024x1024 bf16
  ushort* E16   = (ushort*)(wsb + 49997056);  // 7 x 1000x640 bf16

  hipMemsetAsync(wsb, 0, 2818304, stream);

  // ---- weight conversions ----
  {
    ConvJobs a = {};
    const float* hin[11] = {enc_Ur, enc_Uz, enc_U, dec_Ur, dec_Uz, dec_U,
                            dec_Cr, dec_Cz, dec_C, C_o, W_s};
    const float* ein[7]  = {enc_Wr, enc_Wz, enc_W, dec_Wr, dec_Wz, dec_W, V_o};
    for (int i = 0; i < 11; ++i) {
      a.in[i] = hin[i]; a.out[i] = H16 + (size_t)i * 1024 * HP_;
      a.K[i] = H_; a.Kp[i] = HP_; a.vrows[i] = 1000; a.arows[i] = 1024;
    }
    for (int i = 0; i < 7; ++i) {
      a.in[11 + i] = ein[i]; a.out[11 + i] = E16 + (size_t)i * 1000 * EP_;
      a.K[11 + i] = E_; a.Kp[11 + i] = EP_; a.vrows[11 + i] = 1000; a.arows[11 + i] = 1000;
    }
    conv_small<<<dim3(1024, 18), dim3(256), 0, stream>>>(a);
  }

  gather16<<<dim3(2 * S_ * B_), dim3(256), 0, stream>>>(src, tgt, src_emb, tgt_emb, XE16, YE16);

  // ---- batched input projections: M=768 N=1000 Kp=640 ----
  {
    MG g = {};
    const ushort* As[7] = {XE16, XE16, XE16, YE16, YE16, YE16, YE16};
    float* Cs[7] = {XPr, XPz, XPc, YPr, YPz, YPc, YV};
    for (int i = 0; i < 7; ++i) {
      g.A[i] = As[i]; g.Bw[i] = E16 + (size_t)i * 1000 * EP_; g.C[i] = Cs[i];
    }
    g.M = S_ * B_; g.N = H_; g.Kp = EP_; g.ldc = H_; g.mode = 0;
    mgemm<<<dim3(8, 6, 7), dim3(256), 0, stream>>>(g);
  }

  // ---- persistent recurrence (cooperative) ----
  {
    RecArgs ra = {};
    ra.encUr = H16 + 0ull * 1024 * HP_;
    ra.encUz = H16 + 1ull * 1024 * HP_;
    ra.encU  = H16 + 2ull * 1024 * HP_;
    ra.decUr = H16 + 3ull * 1024 * HP_;
    ra.decUz = H16 + 4ull * 1024 * HP_;
    ra.decU  = H16 + 5ull * 1024 * HP_;
    ra.cW0 = H16 + 6ull * 1024 * HP_;   // dec_Cr
    ra.cW1 = H16 + 7ull * 1024 * HP_;   // dec_Cz
    ra.cW2 = H16 + 8ull * 1024 * HP_;   // dec_C
    ra.cW3 = H16 + 9ull * 1024 * HP_;   // C_o
    ra.cW4 = H16 + 10ull * 1024 * HP_;  // W_s
    ra.XPr = XPr; ra.XPz = XPz; ra.XPc = XPc;
    ra.YPr = YPr; ra.YPz = YPz; ra.YPc = YPc;
    ra.enc_b = enc_b; ra.enc_bz = enc_bz; ra.enc_br = enc_br;
    ra.dec_b = dec_b; ra.dec_bz = dec_bz; ra.dec_br = dec_br;
    ra.hf = hf; ra.h16 = h16; ra.sdf = sdf; ra.hd16 = hd16;
    ra.rh16 = rh16; ra.zbuf = zbuf;
    ra.cCr = cCr; ra.cCz = cCz; ra.cC = cC; ra.cCo = cCo;
    ra.Srm = Srm16; ra.bar = bar;
    void* kp[] = {&ra};
    hipLaunchCooperativeKernel(rnn_rec, dim3(NB_), dim3(256), kp, 0, stream);
  }

  // ---- maxout GEMM: t = Srm@U_o^T + YV + cCo -> Tmax bf16 [768][512] ----
  {
    MG g = {};
    g.A[0] = Srm16;
    g.BwF = U_o; g.bF32 = 1; g.Kreal = 1000; g.ldbF = 1000;
    g.M = T_ * B_; g.N = M2_; g.Kp = HP_; g.ldc = 0; g.mode = 1;
    g.e1 = YV; g.e2 = cCo; g.tmax = Tmax;
    mgemm<<<dim3(8, 6, 1), dim3(256), 0, stream>>>(g);
  }

  // ---- logits = Tmax @ W_o^T -> out[b][t][v] (XCD-swizzled 1-D grid) ----
  {
    MG g = {};
    g.A[0] = Tmax; g.C[0] = out;
    g.BwF = W_o; g.bF32 = 1; g.Kreal = 500; g.ldbF = 500;
    g.M = T_ * B_; g.N = V_; g.Kp = KW_; g.ldc = V_; g.mode = 2;
    g.swz = 1;
    mgemm<<<dim3(1440, 1, 1), dim3(256), 0, stream>>>(g);
  }
}